// Round 5
// baseline (7238.625 us; speedup 1.0000x reference)
//
#include <hip/hip_runtime.h>
#include <hip/hip_bf16.h>
#include <math.h>

// ---------------------------------------------------------------------------
// GraphSAGE 3-layer, HIDDEN=64, mean aggregation.
// R5: split gather / dense again (R4 fusion was LDS-pipe + occupancy bound).
//   gather_mean: bf16 h-table gather (205MB/layer, 12.8MB table), f32 accum.
//   dense_out:   out = elu(agg@Wl + b + h@Wr), f32 VALU GEMM, 64-row tiles,
//                float4 LDS reads, writes f32 + bf16 copy for next gather.
// CSR: count/scan/fill; fill uses atomicSub(cnt) (no cursor buf, no invd).
// ---------------------------------------------------------------------------

#define HID 64

__device__ __forceinline__ float b2f(unsigned short u) {
    unsigned int t = ((unsigned int)u) << 16;
    return __uint_as_float(t);
}
__device__ __forceinline__ unsigned short f2b(float f) {
    unsigned int u = __float_as_uint(f);
    u = (u + 0x7FFF + ((u >> 16) & 1)) >> 16;   // RNE
    return (unsigned short)u;
}

// ---- CSR build ------------------------------------------------------------

__global__ void count_deg(const int* __restrict__ dst, int* __restrict__ cnt, int E) {
    int e = blockIdx.x * blockDim.x + threadIdx.x;
    if (e < E) atomicAdd(&cnt[dst[e]], 1);
}

__global__ void scan_partials(const int* __restrict__ cnt, int* __restrict__ bsum, int n) {
    __shared__ int lsum[256];
    int t = threadIdx.x;
    int base = blockIdx.x * 1024 + t * 4;
    int s = 0;
    if (base + 3 < n) {
        int4 v = *(const int4*)&cnt[base];
        s = v.x + v.y + v.z + v.w;
    } else {
        for (int i = 0; i < 4; ++i) if (base + i < n) s += cnt[base + i];
    }
    lsum[t] = s;
    __syncthreads();
    for (int off = 128; off > 0; off >>= 1) {
        if (t < off) lsum[t] += lsum[t + off];
        __syncthreads();
    }
    if (t == 0) bsum[blockIdx.x] = lsum[0];
}

__global__ void scan_tops(int* __restrict__ bsum, int* __restrict__ offs_last,
                          int nb, int E) {
    __shared__ int s[128];
    int t = threadIdx.x;
    s[t] = (t < nb) ? bsum[t] : 0;
    __syncthreads();
    for (int off = 1; off < 128; off <<= 1) {
        int v = (t >= off) ? s[t - off] : 0;
        __syncthreads();
        s[t] += v;
        __syncthreads();
    }
    if (t < nb) bsum[t] = (t == 0) ? 0 : s[t - 1];
    if (t == 0) *offs_last = E;
}

__global__ void scan_write(const int* __restrict__ cnt, const int* __restrict__ bsum,
                           int* __restrict__ offs, int n) {
    __shared__ int lsum[256];
    int t = threadIdx.x;
    int base = blockIdx.x * 1024 + t * 4;
    int v0 = 0, v1 = 0, v2 = 0, v3 = 0;
    bool full = (base + 3 < n);
    if (full) {
        int4 v = *(const int4*)&cnt[base];
        v0 = v.x; v1 = v.y; v2 = v.z; v3 = v.w;
    } else {
        if (base     < n) v0 = cnt[base];
        if (base + 1 < n) v1 = cnt[base + 1];
        if (base + 2 < n) v2 = cnt[base + 2];
        if (base + 3 < n) v3 = cnt[base + 3];
    }
    lsum[t] = v0 + v1 + v2 + v3;
    __syncthreads();
    for (int off = 1; off < 256; off <<= 1) {
        int u = (t >= off) ? lsum[t - off] : 0;
        __syncthreads();
        lsum[t] += u;
        __syncthreads();
    }
    int ex = bsum[blockIdx.x] + ((t == 0) ? 0 : lsum[t - 1]);
    int o0 = ex, o1 = ex + v0, o2 = o1 + v1, o3 = o2 + v2;
    if (full) {
        *(int4*)&offs[base] = make_int4(o0, o1, o2, o3);
    } else {
        if (base     < n) offs[base]     = o0;
        if (base + 1 < n) offs[base + 1] = o1;
        if (base + 2 < n) offs[base + 2] = o2;
        if (base + 3 < n) offs[base + 3] = o3;
    }
}

// fill via atomicSub on cnt (cnt ends at 0; segment order irrelevant for sum)
__global__ void fill_csr(const int* __restrict__ src, const int* __restrict__ dst,
                         int* __restrict__ cnt, const int* __restrict__ offs,
                         int* __restrict__ csr, int E) {
    int e = blockIdx.x * blockDim.x + threadIdx.x;
    if (e < E) {
        int d = dst[e];
        int p = atomicSub(&cnt[d], 1) - 1;
        csr[offs[d] + p] = src[e];
    }
}

// ---- f32 -> bf16 convert --------------------------------------------------

__global__ void to_bf16(const float* __restrict__ in, unsigned short* __restrict__ o, int n4) {
    int i = blockIdx.x * blockDim.x + threadIdx.x;
    if (i < n4) {
        float4 v = ((const float4*)in)[i];
        ushort4 u;
        u.x = f2b(v.x); u.y = f2b(v.y); u.z = f2b(v.z); u.w = f2b(v.w);
        ((ushort4*)o)[i] = u;
    }
}

// ---- gather: agg[n] = mean_{s in N(n)} h_bf16[s] --------------------------
// wave per node; lane = feature. Indices loaded 64-at-a-time by lanes,
// broadcast via __shfl. 8-deep unrolled row loads. VGPR kept low (8 wv/SIMD).

__launch_bounds__(256)
__global__ void gather_mean(const unsigned short* __restrict__ hb,
                            const int* __restrict__ offs, const int* __restrict__ csr,
                            float* __restrict__ agg, int nnodes) {
    int lane = threadIdx.x & 63;
    int wv   = threadIdx.x >> 6;
    int wid  = blockIdx.x * 4 + wv;
    int nw   = gridDim.x * 4;
    for (int n = wid; n < nnodes; n += nw) {
        int beg = offs[n], end = offs[n + 1];
        int deg = end - beg;
        float a0 = 0.f, a1 = 0.f, a2 = 0.f, a3 = 0.f;
        float a4 = 0.f, a5 = 0.f, a6 = 0.f, a7 = 0.f;
        for (int base = beg; base < end; base += 64) {
            int cnt = min(64, end - base);
            int myi = csr[base + min(lane, cnt - 1)];
            int j = 0;
            for (; j + 8 <= cnt; j += 8) {
                int s0 = __shfl(myi, j + 0), s1 = __shfl(myi, j + 1);
                int s2 = __shfl(myi, j + 2), s3 = __shfl(myi, j + 3);
                int s4 = __shfl(myi, j + 4), s5 = __shfl(myi, j + 5);
                int s6 = __shfl(myi, j + 6), s7 = __shfl(myi, j + 7);
                a0 += b2f(hb[(size_t)s0 * HID + lane]);
                a1 += b2f(hb[(size_t)s1 * HID + lane]);
                a2 += b2f(hb[(size_t)s2 * HID + lane]);
                a3 += b2f(hb[(size_t)s3 * HID + lane]);
                a4 += b2f(hb[(size_t)s4 * HID + lane]);
                a5 += b2f(hb[(size_t)s5 * HID + lane]);
                a6 += b2f(hb[(size_t)s6 * HID + lane]);
                a7 += b2f(hb[(size_t)s7 * HID + lane]);
            }
            for (; j < cnt; ++j) {
                int s = __shfl(myi, j);
                a0 += b2f(hb[(size_t)s * HID + lane]);
            }
        }
        float m = (((a0 + a1) + (a2 + a3)) + ((a4 + a5) + (a6 + a7)))
                  * (1.0f / (float)max(deg, 1));
        agg[(size_t)n * HID + lane] = m;
    }
}

// ---- dense: out = elu(agg@Wl + b + h@Wr), 64-row tile, 4x4/thread ---------

__launch_bounds__(256)
__global__ void dense_out(const float* __restrict__ agg, const float* __restrict__ h,
                          const float* __restrict__ Wl, const float* __restrict__ bl,
                          const float* __restrict__ Wr, float* __restrict__ out,
                          unsigned short* __restrict__ out_bf, int nrows) {
    __shared__ float Wc[64][128];      // [f][c]: c<64 Wl, c>=64 Wr (32 KB)
    __shared__ float a_s[64][68];      // 17.4 KB (68: 16B-aligned pad)
    __shared__ float h_s[64][68];
    __shared__ float bl_s[64];
    int tid = threadIdx.x;

    for (int idx = tid; idx < 4096; idx += 256) {
        int f = idx >> 6, c = idx & 63;
        Wc[f][c]      = Wl[idx];
        Wc[f][64 + c] = Wr[idx];
    }
    if (tid < 64) bl_s[tid] = bl[tid];

    int n0 = blockIdx.x * 64;
    {
        int r  = tid >> 2;            // 0..63
        int f0 = (tid & 3) * 16;      // 0,16,32,48
        if (n0 + r < nrows) {
            const float4* ap = (const float4*)&agg[(size_t)(n0 + r) * HID + f0];
            const float4* hp = (const float4*)&h[(size_t)(n0 + r) * HID + f0];
            float4 A0 = ap[0], A1 = ap[1], A2 = ap[2], A3 = ap[3];
            float4 H0 = hp[0], H1 = hp[1], H2 = hp[2], H3 = hp[3];
            *(float4*)&a_s[r][f0]      = A0;
            *(float4*)&a_s[r][f0 + 4]  = A1;
            *(float4*)&a_s[r][f0 + 8]  = A2;
            *(float4*)&a_s[r][f0 + 12] = A3;
            *(float4*)&h_s[r][f0]      = H0;
            *(float4*)&h_s[r][f0 + 4]  = H1;
            *(float4*)&h_s[r][f0 + 8]  = H2;
            *(float4*)&h_s[r][f0 + 12] = H3;
        } else {
            float4 z = make_float4(0.f, 0.f, 0.f, 0.f);
            *(float4*)&a_s[r][f0]      = z; *(float4*)&a_s[r][f0 + 4]  = z;
            *(float4*)&a_s[r][f0 + 8]  = z; *(float4*)&a_s[r][f0 + 12] = z;
            *(float4*)&h_s[r][f0]      = z; *(float4*)&h_s[r][f0 + 4]  = z;
            *(float4*)&h_s[r][f0 + 8]  = z; *(float4*)&h_s[r][f0 + 12] = z;
        }
    }
    __syncthreads();

    int cg = tid & 15, rg = tid >> 4;
    int c0 = cg * 4, r0 = rg * 4;
    float acc[4][4];
#pragma unroll
    for (int i = 0; i < 4; ++i) {
        acc[i][0] = bl_s[c0];     acc[i][1] = bl_s[c0 + 1];
        acc[i][2] = bl_s[c0 + 2]; acc[i][3] = bl_s[c0 + 3];
    }

#pragma unroll
    for (int fb = 0; fb < 64; fb += 4) {
        float4 ar0 = *(float4*)&a_s[r0 + 0][fb];
        float4 ar1 = *(float4*)&a_s[r0 + 1][fb];
        float4 ar2 = *(float4*)&a_s[r0 + 2][fb];
        float4 ar3 = *(float4*)&a_s[r0 + 3][fb];
        float4 hr0 = *(float4*)&h_s[r0 + 0][fb];
        float4 hr1 = *(float4*)&h_s[r0 + 1][fb];
        float4 hr2 = *(float4*)&h_s[r0 + 2][fb];
        float4 hr3 = *(float4*)&h_s[r0 + 3][fb];
#pragma unroll
        for (int u = 0; u < 4; ++u) {
            float4 wl = *(float4*)&Wc[fb + u][c0];
            float4 wr = *(float4*)&Wc[fb + u][64 + c0];
            float a0v = (&ar0.x)[u], a1v = (&ar1.x)[u], a2v = (&ar2.x)[u], a3v = (&ar3.x)[u];
            float h0v = (&hr0.x)[u], h1v = (&hr1.x)[u], h2v = (&hr2.x)[u], h3v = (&hr3.x)[u];
            acc[0][0] += a0v * wl.x + h0v * wr.x; acc[0][1] += a0v * wl.y + h0v * wr.y;
            acc[0][2] += a0v * wl.z + h0v * wr.z; acc[0][3] += a0v * wl.w + h0v * wr.w;
            acc[1][0] += a1v * wl.x + h1v * wr.x; acc[1][1] += a1v * wl.y + h1v * wr.y;
            acc[1][2] += a1v * wl.z + h1v * wr.z; acc[1][3] += a1v * wl.w + h1v * wr.w;
            acc[2][0] += a2v * wl.x + h2v * wr.x; acc[2][1] += a2v * wl.y + h2v * wr.y;
            acc[2][2] += a2v * wl.z + h2v * wr.z; acc[2][3] += a2v * wl.w + h2v * wr.w;
            acc[3][0] += a3v * wl.x + h3v * wr.x; acc[3][1] += a3v * wl.y + h3v * wr.y;
            acc[3][2] += a3v * wl.z + h3v * wr.z; acc[3][3] += a3v * wl.w + h3v * wr.w;
        }
    }

#pragma unroll
    for (int i = 0; i < 4; ++i) {
        int row = n0 + r0 + i;
        if (row < nrows) {
            float4 o;
            o.x = acc[i][0] > 0.f ? acc[i][0] : expm1f(acc[i][0]);
            o.y = acc[i][1] > 0.f ? acc[i][1] : expm1f(acc[i][1]);
            o.z = acc[i][2] > 0.f ? acc[i][2] : expm1f(acc[i][2]);
            o.w = acc[i][3] > 0.f ? acc[i][3] : expm1f(acc[i][3]);
            *(float4*)&out[(size_t)row * HID + c0] = o;
            if (out_bf) {
                ushort4 u;
                u.x = f2b(o.x); u.y = f2b(o.y); u.z = f2b(o.z); u.w = f2b(o.w);
                *(ushort4*)&out_bf[(size_t)row * HID + c0] = u;
            }
        }
    }
}

// ---- launch ---------------------------------------------------------------

extern "C" void kernel_launch(void* const* d_in, const int* in_sizes, int n_in,
                              void* d_out, int out_size, void* d_ws, size_t ws_size,
                              hipStream_t stream) {
    const float* x   = (const float*)d_in[0];
    const int*   ei  = (const int*)d_in[1];
    const float* Wl1 = (const float*)d_in[2];
    const float* bl1 = (const float*)d_in[3];
    const float* Wr1 = (const float*)d_in[4];
    const float* Wl2 = (const float*)d_in[5];
    const float* bl2 = (const float*)d_in[6];
    const float* Wr2 = (const float*)d_in[7];
    const float* Wl3 = (const float*)d_in[8];
    const float* bl3 = (const float*)d_in[9];
    const float* Wr3 = (const float*)d_in[10];
    float* out = (float*)d_out;

    int N = in_sizes[0] / HID;   // 100000
    int E = in_sizes[1] / 2;     // 1600000
    const int* src = ei;
    const int* dst = ei + E;

    // workspace (~84.0 MB, within proven footprint)
    char* p = (char*)d_ws;
    float*          aggb = (float*)p;          p += (size_t)N * HID * sizeof(float);   // 25.6
    float*          H    = (float*)p;          p += (size_t)N * HID * sizeof(float);   // 25.6
    unsigned short* bfA  = (unsigned short*)p; p += (size_t)N * HID * 2;               // 12.8
    unsigned short* bfB  = (unsigned short*)p; p += (size_t)N * HID * 2;               // 12.8
    int*            csr  = (int*)p;            p += (size_t)E * sizeof(int);           // 6.4
    int*            cnt  = (int*)p;            p += (size_t)N * sizeof(int);
    int*            offs = (int*)p;            p += (size_t)(N + 4) * sizeof(int);
    int*            bsum = (int*)p;            p += 256 * sizeof(int);

    hipMemsetAsync(cnt, 0, (size_t)N * sizeof(int), stream);

    int eb = (E + 255) / 256;
    int sb = (N + 1023) / 1024;
    count_deg<<<eb, 256, 0, stream>>>(dst, cnt, E);
    scan_partials<<<sb, 256, 0, stream>>>(cnt, bsum, N);
    scan_tops<<<1, 128, 0, stream>>>(bsum, &offs[N], sb, E);
    scan_write<<<sb, 256, 0, stream>>>(cnt, bsum, offs, N);
    fill_csr<<<eb, 256, 0, stream>>>(src, dst, cnt, offs, csr, E);

    to_bf16<<<(N * HID / 4 + 255) / 256, 256, 0, stream>>>(x, bfB, N * HID / 4);

    int db = (N + 63) / 64;   // 1563

    // L1: gather(x_bf) -> agg; dense(agg, x) -> H + bfA
    gather_mean<<<2048, 256, 0, stream>>>(bfB, offs, csr, aggb, N);
    dense_out<<<db, 256, 0, stream>>>(aggb, x, Wl1, bl1, Wr1, H, bfA, N);
    // L2: gather(bfA) -> agg; dense(agg, H) -> H (in-place rows) + bfB
    gather_mean<<<2048, 256, 0, stream>>>(bfA, offs, csr, aggb, N);
    dense_out<<<db, 256, 0, stream>>>(aggb, H, Wl2, bl2, Wr2, H, bfB, N);
    // L3: gather(bfB) -> agg; dense(agg, H) -> out (f32, no bf16 copy)
    gather_mean<<<2048, 256, 0, stream>>>(bfB, offs, csr, aggb, N);
    dense_out<<<db, 256, 0, stream>>>(aggb, H, Wl3, bl3, Wr3, out, (unsigned short*)nullptr, N);
}

// Round 6
// 529.547 us; speedup vs baseline: 13.6695x; 13.6695x over previous
//
#include <hip/hip_runtime.h>
#include <hip/hip_bf16.h>
#include <math.h>

// ---------------------------------------------------------------------------
// GraphSAGE 3-layer, HIDDEN=64, mean aggregation.
// R6: fix R5's dense_out register blowup (VGPR=256, 4GB spill fetch).
//   dense_cat: out = elu([agg|h] @ [[Wl];[Wr]] + b)  -- K=128 GEMM, 32-row
//   tile, acc[2][4]/thread, 48.8KB LDS, staging via strided loop (no big
//   live sets). Structure mirrors the proven R3 gemm_y.
//   gather_mean: unchanged (bf16 table, f32 accum).
// ---------------------------------------------------------------------------

#define HID 64

__device__ __forceinline__ float b2f(unsigned short u) {
    unsigned int t = ((unsigned int)u) << 16;
    return __uint_as_float(t);
}
__device__ __forceinline__ unsigned short f2b(float f) {
    unsigned int u = __float_as_uint(f);
    u = (u + 0x7FFF + ((u >> 16) & 1)) >> 16;   // RNE
    return (unsigned short)u;
}

// ---- CSR build ------------------------------------------------------------

__global__ void count_deg(const int* __restrict__ dst, int* __restrict__ cnt, int E) {
    int e = blockIdx.x * blockDim.x + threadIdx.x;
    if (e < E) atomicAdd(&cnt[dst[e]], 1);
}

__global__ void scan_partials(const int* __restrict__ cnt, int* __restrict__ bsum, int n) {
    __shared__ int lsum[256];
    int t = threadIdx.x;
    int base = blockIdx.x * 1024 + t * 4;
    int s = 0;
    if (base + 3 < n) {
        int4 v = *(const int4*)&cnt[base];
        s = v.x + v.y + v.z + v.w;
    } else {
        for (int i = 0; i < 4; ++i) if (base + i < n) s += cnt[base + i];
    }
    lsum[t] = s;
    __syncthreads();
    for (int off = 128; off > 0; off >>= 1) {
        if (t < off) lsum[t] += lsum[t + off];
        __syncthreads();
    }
    if (t == 0) bsum[blockIdx.x] = lsum[0];
}

__global__ void scan_tops(int* __restrict__ bsum, int* __restrict__ offs_last,
                          int nb, int E) {
    __shared__ int s[128];
    int t = threadIdx.x;
    s[t] = (t < nb) ? bsum[t] : 0;
    __syncthreads();
    for (int off = 1; off < 128; off <<= 1) {
        int v = (t >= off) ? s[t - off] : 0;
        __syncthreads();
        s[t] += v;
        __syncthreads();
    }
    if (t < nb) bsum[t] = (t == 0) ? 0 : s[t - 1];
    if (t == 0) *offs_last = E;
}

__global__ void scan_write(const int* __restrict__ cnt, const int* __restrict__ bsum,
                           int* __restrict__ offs, int n) {
    __shared__ int lsum[256];
    int t = threadIdx.x;
    int base = blockIdx.x * 1024 + t * 4;
    int v0 = 0, v1 = 0, v2 = 0, v3 = 0;
    bool full = (base + 3 < n);
    if (full) {
        int4 v = *(const int4*)&cnt[base];
        v0 = v.x; v1 = v.y; v2 = v.z; v3 = v.w;
    } else {
        if (base     < n) v0 = cnt[base];
        if (base + 1 < n) v1 = cnt[base + 1];
        if (base + 2 < n) v2 = cnt[base + 2];
        if (base + 3 < n) v3 = cnt[base + 3];
    }
    lsum[t] = v0 + v1 + v2 + v3;
    __syncthreads();
    for (int off = 1; off < 256; off <<= 1) {
        int u = (t >= off) ? lsum[t - off] : 0;
        __syncthreads();
        lsum[t] += u;
        __syncthreads();
    }
    int ex = bsum[blockIdx.x] + ((t == 0) ? 0 : lsum[t - 1]);
    int o0 = ex, o1 = ex + v0, o2 = o1 + v1, o3 = o2 + v2;
    if (full) {
        *(int4*)&offs[base] = make_int4(o0, o1, o2, o3);
    } else {
        if (base     < n) offs[base]     = o0;
        if (base + 1 < n) offs[base + 1] = o1;
        if (base + 2 < n) offs[base + 2] = o2;
        if (base + 3 < n) offs[base + 3] = o3;
    }
}

__global__ void fill_csr(const int* __restrict__ src, const int* __restrict__ dst,
                         int* __restrict__ cnt, const int* __restrict__ offs,
                         int* __restrict__ csr, int E) {
    int e = blockIdx.x * blockDim.x + threadIdx.x;
    if (e < E) {
        int d = dst[e];
        int p = atomicSub(&cnt[d], 1) - 1;
        csr[offs[d] + p] = src[e];
    }
}

// ---- f32 -> bf16 convert --------------------------------------------------

__global__ void to_bf16(const float* __restrict__ in, unsigned short* __restrict__ o, int n4) {
    int i = blockIdx.x * blockDim.x + threadIdx.x;
    if (i < n4) {
        float4 v = ((const float4*)in)[i];
        ushort4 u;
        u.x = f2b(v.x); u.y = f2b(v.y); u.z = f2b(v.z); u.w = f2b(v.w);
        ((ushort4*)o)[i] = u;
    }
}

// ---- gather: agg[n] = mean_{s in N(n)} h_bf16[s] --------------------------

__launch_bounds__(256)
__global__ void gather_mean(const unsigned short* __restrict__ hb,
                            const int* __restrict__ offs, const int* __restrict__ csr,
                            float* __restrict__ agg, int nnodes) {
    int lane = threadIdx.x & 63;
    int wv   = threadIdx.x >> 6;
    int wid  = blockIdx.x * 4 + wv;
    int nw   = gridDim.x * 4;
    for (int n = wid; n < nnodes; n += nw) {
        int beg = offs[n], end = offs[n + 1];
        int deg = end - beg;
        float a0 = 0.f, a1 = 0.f, a2 = 0.f, a3 = 0.f;
        float a4 = 0.f, a5 = 0.f, a6 = 0.f, a7 = 0.f;
        for (int base = beg; base < end; base += 64) {
            int cnt = min(64, end - base);
            int myi = csr[base + min(lane, cnt - 1)];
            int j = 0;
            for (; j + 8 <= cnt; j += 8) {
                int s0 = __shfl(myi, j + 0), s1 = __shfl(myi, j + 1);
                int s2 = __shfl(myi, j + 2), s3 = __shfl(myi, j + 3);
                int s4 = __shfl(myi, j + 4), s5 = __shfl(myi, j + 5);
                int s6 = __shfl(myi, j + 6), s7 = __shfl(myi, j + 7);
                a0 += b2f(hb[(size_t)s0 * HID + lane]);
                a1 += b2f(hb[(size_t)s1 * HID + lane]);
                a2 += b2f(hb[(size_t)s2 * HID + lane]);
                a3 += b2f(hb[(size_t)s3 * HID + lane]);
                a4 += b2f(hb[(size_t)s4 * HID + lane]);
                a5 += b2f(hb[(size_t)s5 * HID + lane]);
                a6 += b2f(hb[(size_t)s6 * HID + lane]);
                a7 += b2f(hb[(size_t)s7 * HID + lane]);
            }
            for (; j < cnt; ++j) {
                int s = __shfl(myi, j);
                a0 += b2f(hb[(size_t)s * HID + lane]);
            }
        }
        float m = (((a0 + a1) + (a2 + a3)) + ((a4 + a5) + (a6 + a7)))
                  * (1.0f / (float)max(deg, 1));
        agg[(size_t)n * HID + lane] = m;
    }
}

// ---- dense: out = elu([agg|h] @ [[Wl];[Wr]] + b) --------------------------
// K=128 GEMM. 32-row tile, 64 cols, 256 threads, acc[2][4] per thread.
// LDS: W_s 32KB + cat_s 16.9KB + bias = 48.8KB -> 3 blocks/CU.

__launch_bounds__(256)
__global__ void dense_cat(const float* __restrict__ agg, const float* __restrict__ h,
                          const float* __restrict__ Wl, const float* __restrict__ bl,
                          const float* __restrict__ Wr, float* __restrict__ out,
                          unsigned short* __restrict__ out_bf, int nrows) {
    __shared__ float W_s[128][64];     // rows 0..63 = Wl[f][c], 64..127 = Wr[f][c]
    __shared__ float cat_s[32][132];   // cols 0..63 = agg row, 64..127 = h row
    __shared__ float bl_s[64];
    int tid = threadIdx.x;
    int n0  = blockIdx.x * 32;

    // stage W: 2048 float4 slots, 8 per thread (coalesced 16B)
    for (int idx = tid; idx < 2048; idx += 256) {
        int f = idx >> 4, c4 = (idx & 15) * 4;
        const float* Wsrc = (f < 64) ? (Wl + f * 64 + c4) : (Wr + (f - 64) * 64 + c4);
        *(float4*)&W_s[f][c4] = *(const float4*)Wsrc;
    }
    if (tid < 64) bl_s[tid] = bl[tid];

    // stage cat rows: 32 rows x 32 float4 slots, 4 per thread
    for (int idx = tid; idx < 1024; idx += 256) {
        int r = idx >> 5, c4 = idx & 31;
        float4 v = make_float4(0.f, 0.f, 0.f, 0.f);
        if (n0 + r < nrows) {
            const float* srcp = (c4 < 16) ? (agg + (size_t)(n0 + r) * HID + c4 * 4)
                                          : (h   + (size_t)(n0 + r) * HID + (c4 - 16) * 4);
            v = *(const float4*)srcp;
        }
        *(float4*)&cat_s[r][c4 * 4] = v;
    }
    __syncthreads();

    int cg = tid & 15, rg = tid >> 4;
    int c0 = cg * 4, r0 = rg * 2;
    float acc0x = 0.f, acc0y = 0.f, acc0z = 0.f, acc0w = 0.f;
    float acc1x = 0.f, acc1y = 0.f, acc1z = 0.f, acc1w = 0.f;

    for (int k = 0; k < 128; k += 4) {
        float4 a0 = *(float4*)&cat_s[r0 + 0][k];
        float4 a1 = *(float4*)&cat_s[r0 + 1][k];
#pragma unroll
        for (int u = 0; u < 4; ++u) {
            float4 w = *(float4*)&W_s[k + u][c0];
            float av0 = (&a0.x)[u], av1 = (&a1.x)[u];
            acc0x += av0 * w.x; acc0y += av0 * w.y;
            acc0z += av0 * w.z; acc0w += av0 * w.w;
            acc1x += av1 * w.x; acc1y += av1 * w.y;
            acc1z += av1 * w.z; acc1w += av1 * w.w;
        }
    }

    float bx = bl_s[c0], by = bl_s[c0 + 1], bz = bl_s[c0 + 2], bw = bl_s[c0 + 3];
#pragma unroll
    for (int i = 0; i < 2; ++i) {
        int row = n0 + r0 + i;
        if (row < nrows) {
            float4 o;
            o.x = (i ? acc1x : acc0x) + bx;
            o.y = (i ? acc1y : acc0y) + by;
            o.z = (i ? acc1z : acc0z) + bz;
            o.w = (i ? acc1w : acc0w) + bw;
            o.x = o.x > 0.f ? o.x : expm1f(o.x);
            o.y = o.y > 0.f ? o.y : expm1f(o.y);
            o.z = o.z > 0.f ? o.z : expm1f(o.z);
            o.w = o.w > 0.f ? o.w : expm1f(o.w);
            *(float4*)&out[(size_t)row * HID + c0] = o;
            if (out_bf) {
                ushort4 u;
                u.x = f2b(o.x); u.y = f2b(o.y); u.z = f2b(o.z); u.w = f2b(o.w);
                *(ushort4*)&out_bf[(size_t)row * HID + c0] = u;
            }
        }
    }
}

// ---- launch ---------------------------------------------------------------

extern "C" void kernel_launch(void* const* d_in, const int* in_sizes, int n_in,
                              void* d_out, int out_size, void* d_ws, size_t ws_size,
                              hipStream_t stream) {
    const float* x   = (const float*)d_in[0];
    const int*   ei  = (const int*)d_in[1];
    const float* Wl1 = (const float*)d_in[2];
    const float* bl1 = (const float*)d_in[3];
    const float* Wr1 = (const float*)d_in[4];
    const float* Wl2 = (const float*)d_in[5];
    const float* bl2 = (const float*)d_in[6];
    const float* Wr2 = (const float*)d_in[7];
    const float* Wl3 = (const float*)d_in[8];
    const float* bl3 = (const float*)d_in[9];
    const float* Wr3 = (const float*)d_in[10];
    float* out = (float*)d_out;

    int N = in_sizes[0] / HID;   // 100000
    int E = in_sizes[1] / 2;     // 1600000
    const int* src = ei;
    const int* dst = ei + E;

    // workspace (~84 MB)
    char* p = (char*)d_ws;
    float*          aggb = (float*)p;          p += (size_t)N * HID * sizeof(float);
    float*          H    = (float*)p;          p += (size_t)N * HID * sizeof(float);
    unsigned short* bfA  = (unsigned short*)p; p += (size_t)N * HID * 2;
    unsigned short* bfB  = (unsigned short*)p; p += (size_t)N * HID * 2;
    int*            csr  = (int*)p;            p += (size_t)E * sizeof(int);
    int*            cnt  = (int*)p;            p += (size_t)N * sizeof(int);
    int*            offs = (int*)p;            p += (size_t)(N + 4) * sizeof(int);
    int*            bsum = (int*)p;            p += 256 * sizeof(int);

    hipMemsetAsync(cnt, 0, (size_t)N * sizeof(int), stream);

    int eb = (E + 255) / 256;
    int sb = (N + 1023) / 1024;
    count_deg<<<eb, 256, 0, stream>>>(dst, cnt, E);
    scan_partials<<<sb, 256, 0, stream>>>(cnt, bsum, N);
    scan_tops<<<1, 128, 0, stream>>>(bsum, &offs[N], sb, E);
    scan_write<<<sb, 256, 0, stream>>>(cnt, bsum, offs, N);
    fill_csr<<<eb, 256, 0, stream>>>(src, dst, cnt, offs, csr, E);

    to_bf16<<<(N * HID / 4 + 255) / 256, 256, 0, stream>>>(x, bfB, N * HID / 4);

    int db = (N + 31) / 32;   // 3125

    gather_mean<<<2048, 256, 0, stream>>>(bfB, offs, csr, aggb, N);
    dense_cat<<<db, 256, 0, stream>>>(aggb, x, Wl1, bl1, Wr1, H, bfA, N);

    gather_mean<<<2048, 256, 0, stream>>>(bfA, offs, csr, aggb, N);
    dense_cat<<<db, 256, 0, stream>>>(aggb, H, Wl2, bl2, Wr2, H, bfB, N);

    gather_mean<<<2048, 256, 0, stream>>>(bfB, offs, csr, aggb, N);
    dense_cat<<<db, 256, 0, stream>>>(aggb, H, Wl3, bl3, Wr3, out, (unsigned short*)nullptr, N);
}

// Round 7
// 490.602 us; speedup vs baseline: 14.7546x; 1.0794x over previous
//
#include <hip/hip_runtime.h>
#include <hip/hip_bf16.h>
#include <math.h>

// ---------------------------------------------------------------------------
// GraphSAGE 3-layer, HIDDEN=64, mean aggregation.
// R7: XCD-partitioned CSR build. fill_csr's 107MB WRITE (16.7x amplification)
// came from csr lines bouncing across 8 non-coherent L2s. Now wg group
// g = wgid&7 (round-robin wg->XCD) handles only dst range g, so each csr
// slab (~800KB) is written by one XCD and lines fill before eviction.
// count_deg gets the same treatment. Rest unchanged from R6 (529us).
// ---------------------------------------------------------------------------

#define HID 64

__device__ __forceinline__ float b2f(unsigned short u) {
    unsigned int t = ((unsigned int)u) << 16;
    return __uint_as_float(t);
}
__device__ __forceinline__ unsigned short f2b(float f) {
    unsigned int u = __float_as_uint(f);
    u = (u + 0x7FFF + ((u >> 16) & 1)) >> 16;   // RNE
    return (unsigned short)u;
}

// ---- CSR build (XCD-partitioned scatter) ----------------------------------
// grid = 8 * M wgs; group g = wgid & 7 lands on XCD g (round-robin dispatch).
// chunk c = wgid >> 3 scans edges [c*CE, (c+1)*CE); processes only edges
// whose dst is in [g*range, (g+1)*range).

__global__ void count_deg_x(const int* __restrict__ dst, int* __restrict__ cnt,
                            int E, int CE, int range, int N) {
    int g = blockIdx.x & 7;
    int c = blockIdx.x >> 3;
    int lo = g * range, hi = min(lo + range, N);
    int e_end = min((c + 1) * CE, E);
    for (int e = c * CE + threadIdx.x; e < e_end; e += 256) {
        int d = dst[e];
        if (d >= lo && d < hi) atomicAdd(&cnt[d], 1);
    }
}

__global__ void fill_csr_x(const int* __restrict__ src, const int* __restrict__ dst,
                           int* __restrict__ cnt, const int* __restrict__ offs,
                           int* __restrict__ csr, int E, int CE, int range, int N) {
    int g = blockIdx.x & 7;
    int c = blockIdx.x >> 3;
    int lo = g * range, hi = min(lo + range, N);
    int e_end = min((c + 1) * CE, E);
    for (int e = c * CE + threadIdx.x; e < e_end; e += 256) {
        int d = dst[e];
        if (d >= lo && d < hi) {
            int p = atomicSub(&cnt[d], 1) - 1;
            csr[offs[d] + p] = src[e];
        }
    }
}

// ---- scan ------------------------------------------------------------------

__global__ void scan_partials(const int* __restrict__ cnt, int* __restrict__ bsum, int n) {
    __shared__ int lsum[256];
    int t = threadIdx.x;
    int base = blockIdx.x * 1024 + t * 4;
    int s = 0;
    if (base + 3 < n) {
        int4 v = *(const int4*)&cnt[base];
        s = v.x + v.y + v.z + v.w;
    } else {
        for (int i = 0; i < 4; ++i) if (base + i < n) s += cnt[base + i];
    }
    lsum[t] = s;
    __syncthreads();
    for (int off = 128; off > 0; off >>= 1) {
        if (t < off) lsum[t] += lsum[t + off];
        __syncthreads();
    }
    if (t == 0) bsum[blockIdx.x] = lsum[0];
}

__global__ void scan_tops(int* __restrict__ bsum, int* __restrict__ offs_last,
                          int nb, int E) {
    __shared__ int s[128];
    int t = threadIdx.x;
    s[t] = (t < nb) ? bsum[t] : 0;
    __syncthreads();
    for (int off = 1; off < 128; off <<= 1) {
        int v = (t >= off) ? s[t - off] : 0;
        __syncthreads();
        s[t] += v;
        __syncthreads();
    }
    if (t < nb) bsum[t] = (t == 0) ? 0 : s[t - 1];
    if (t == 0) *offs_last = E;
}

__global__ void scan_write(const int* __restrict__ cnt, const int* __restrict__ bsum,
                           int* __restrict__ offs, int n) {
    __shared__ int lsum[256];
    int t = threadIdx.x;
    int base = blockIdx.x * 1024 + t * 4;
    int v0 = 0, v1 = 0, v2 = 0, v3 = 0;
    bool full = (base + 3 < n);
    if (full) {
        int4 v = *(const int4*)&cnt[base];
        v0 = v.x; v1 = v.y; v2 = v.z; v3 = v.w;
    } else {
        if (base     < n) v0 = cnt[base];
        if (base + 1 < n) v1 = cnt[base + 1];
        if (base + 2 < n) v2 = cnt[base + 2];
        if (base + 3 < n) v3 = cnt[base + 3];
    }
    lsum[t] = v0 + v1 + v2 + v3;
    __syncthreads();
    for (int off = 1; off < 256; off <<= 1) {
        int u = (t >= off) ? lsum[t - off] : 0;
        __syncthreads();
        lsum[t] += u;
        __syncthreads();
    }
    int ex = bsum[blockIdx.x] + ((t == 0) ? 0 : lsum[t - 1]);
    int o0 = ex, o1 = ex + v0, o2 = o1 + v1, o3 = o2 + v2;
    if (full) {
        *(int4*)&offs[base] = make_int4(o0, o1, o2, o3);
    } else {
        if (base     < n) offs[base]     = o0;
        if (base + 1 < n) offs[base + 1] = o1;
        if (base + 2 < n) offs[base + 2] = o2;
        if (base + 3 < n) offs[base + 3] = o3;
    }
}

// ---- f32 -> bf16 convert --------------------------------------------------

__global__ void to_bf16(const float* __restrict__ in, unsigned short* __restrict__ o, int n4) {
    int i = blockIdx.x * blockDim.x + threadIdx.x;
    if (i < n4) {
        float4 v = ((const float4*)in)[i];
        ushort4 u;
        u.x = f2b(v.x); u.y = f2b(v.y); u.z = f2b(v.z); u.w = f2b(v.w);
        ((ushort4*)o)[i] = u;
    }
}

// ---- gather: agg[n] = mean_{s in N(n)} h_bf16[s] --------------------------

__launch_bounds__(256)
__global__ void gather_mean(const unsigned short* __restrict__ hb,
                            const int* __restrict__ offs, const int* __restrict__ csr,
                            float* __restrict__ agg, int nnodes) {
    int lane = threadIdx.x & 63;
    int wv   = threadIdx.x >> 6;
    int wid  = blockIdx.x * 4 + wv;
    int nw   = gridDim.x * 4;
    for (int n = wid; n < nnodes; n += nw) {
        int beg = offs[n], end = offs[n + 1];
        int deg = end - beg;
        float a0 = 0.f, a1 = 0.f, a2 = 0.f, a3 = 0.f;
        float a4 = 0.f, a5 = 0.f, a6 = 0.f, a7 = 0.f;
        for (int base = beg; base < end; base += 64) {
            int cnt = min(64, end - base);
            int myi = csr[base + min(lane, cnt - 1)];
            int j = 0;
            for (; j + 8 <= cnt; j += 8) {
                int s0 = __shfl(myi, j + 0), s1 = __shfl(myi, j + 1);
                int s2 = __shfl(myi, j + 2), s3 = __shfl(myi, j + 3);
                int s4 = __shfl(myi, j + 4), s5 = __shfl(myi, j + 5);
                int s6 = __shfl(myi, j + 6), s7 = __shfl(myi, j + 7);
                a0 += b2f(hb[(size_t)s0 * HID + lane]);
                a1 += b2f(hb[(size_t)s1 * HID + lane]);
                a2 += b2f(hb[(size_t)s2 * HID + lane]);
                a3 += b2f(hb[(size_t)s3 * HID + lane]);
                a4 += b2f(hb[(size_t)s4 * HID + lane]);
                a5 += b2f(hb[(size_t)s5 * HID + lane]);
                a6 += b2f(hb[(size_t)s6 * HID + lane]);
                a7 += b2f(hb[(size_t)s7 * HID + lane]);
            }
            for (; j < cnt; ++j) {
                int s = __shfl(myi, j);
                a0 += b2f(hb[(size_t)s * HID + lane]);
            }
        }
        float m = (((a0 + a1) + (a2 + a3)) + ((a4 + a5) + (a6 + a7)))
                  * (1.0f / (float)max(deg, 1));
        agg[(size_t)n * HID + lane] = m;
    }
}

// ---- dense: out = elu([agg|h] @ [[Wl];[Wr]] + b) --------------------------

__launch_bounds__(256)
__global__ void dense_cat(const float* __restrict__ agg, const float* __restrict__ h,
                          const float* __restrict__ Wl, const float* __restrict__ bl,
                          const float* __restrict__ Wr, float* __restrict__ out,
                          unsigned short* __restrict__ out_bf, int nrows) {
    __shared__ float W_s[128][64];
    __shared__ float cat_s[32][132];
    __shared__ float bl_s[64];
    int tid = threadIdx.x;
    int n0  = blockIdx.x * 32;

    for (int idx = tid; idx < 2048; idx += 256) {
        int f = idx >> 4, c4 = (idx & 15) * 4;
        const float* Wsrc = (f < 64) ? (Wl + f * 64 + c4) : (Wr + (f - 64) * 64 + c4);
        *(float4*)&W_s[f][c4] = *(const float4*)Wsrc;
    }
    if (tid < 64) bl_s[tid] = bl[tid];

    for (int idx = tid; idx < 1024; idx += 256) {
        int r = idx >> 5, c4 = idx & 31;
        float4 v = make_float4(0.f, 0.f, 0.f, 0.f);
        if (n0 + r < nrows) {
            const float* srcp = (c4 < 16) ? (agg + (size_t)(n0 + r) * HID + c4 * 4)
                                          : (h   + (size_t)(n0 + r) * HID + (c4 - 16) * 4);
            v = *(const float4*)srcp;
        }
        *(float4*)&cat_s[r][c4 * 4] = v;
    }
    __syncthreads();

    int cg = tid & 15, rg = tid >> 4;
    int c0 = cg * 4, r0 = rg * 2;
    float acc0x = 0.f, acc0y = 0.f, acc0z = 0.f, acc0w = 0.f;
    float acc1x = 0.f, acc1y = 0.f, acc1z = 0.f, acc1w = 0.f;

    for (int k = 0; k < 128; k += 4) {
        float4 a0 = *(float4*)&cat_s[r0 + 0][k];
        float4 a1 = *(float4*)&cat_s[r0 + 1][k];
#pragma unroll
        for (int u = 0; u < 4; ++u) {
            float4 w = *(float4*)&W_s[k + u][c0];
            float av0 = (&a0.x)[u], av1 = (&a1.x)[u];
            acc0x += av0 * w.x; acc0y += av0 * w.y;
            acc0z += av0 * w.z; acc0w += av0 * w.w;
            acc1x += av1 * w.x; acc1y += av1 * w.y;
            acc1z += av1 * w.z; acc1w += av1 * w.w;
        }
    }

    float bx = bl_s[c0], by = bl_s[c0 + 1], bz = bl_s[c0 + 2], bw = bl_s[c0 + 3];
#pragma unroll
    for (int i = 0; i < 2; ++i) {
        int row = n0 + r0 + i;
        if (row < nrows) {
            float4 o;
            o.x = (i ? acc1x : acc0x) + bx;
            o.y = (i ? acc1y : acc0y) + by;
            o.z = (i ? acc1z : acc0z) + bz;
            o.w = (i ? acc1w : acc0w) + bw;
            o.x = o.x > 0.f ? o.x : expm1f(o.x);
            o.y = o.y > 0.f ? o.y : expm1f(o.y);
            o.z = o.z > 0.f ? o.z : expm1f(o.z);
            o.w = o.w > 0.f ? o.w : expm1f(o.w);
            *(float4*)&out[(size_t)row * HID + c0] = o;
            if (out_bf) {
                ushort4 u;
                u.x = f2b(o.x); u.y = f2b(o.y); u.z = f2b(o.z); u.w = f2b(o.w);
                *(ushort4*)&out_bf[(size_t)row * HID + c0] = u;
            }
        }
    }
}

// ---- launch ---------------------------------------------------------------

extern "C" void kernel_launch(void* const* d_in, const int* in_sizes, int n_in,
                              void* d_out, int out_size, void* d_ws, size_t ws_size,
                              hipStream_t stream) {
    const float* x   = (const float*)d_in[0];
    const int*   ei  = (const int*)d_in[1];
    const float* Wl1 = (const float*)d_in[2];
    const float* bl1 = (const float*)d_in[3];
    const float* Wr1 = (const float*)d_in[4];
    const float* Wl2 = (const float*)d_in[5];
    const float* bl2 = (const float*)d_in[6];
    const float* Wr2 = (const float*)d_in[7];
    const float* Wl3 = (const float*)d_in[8];
    const float* bl3 = (const float*)d_in[9];
    const float* Wr3 = (const float*)d_in[10];
    float* out = (float*)d_out;

    int N = in_sizes[0] / HID;   // 100000
    int E = in_sizes[1] / 2;     // 1600000
    const int* src = ei;
    const int* dst = ei + E;

    // workspace (~84 MB)
    char* p = (char*)d_ws;
    float*          aggb = (float*)p;          p += (size_t)N * HID * sizeof(float);
    float*          H    = (float*)p;          p += (size_t)N * HID * sizeof(float);
    unsigned short* bfA  = (unsigned short*)p; p += (size_t)N * HID * 2;
    unsigned short* bfB  = (unsigned short*)p; p += (size_t)N * HID * 2;
    int*            csr  = (int*)p;            p += (size_t)E * sizeof(int);
    int*            cnt  = (int*)p;            p += (size_t)N * sizeof(int);
    int*            offs = (int*)p;            p += (size_t)(N + 4) * sizeof(int);
    int*            bsum = (int*)p;            p += 256 * sizeof(int);

    hipMemsetAsync(cnt, 0, (size_t)N * sizeof(int), stream);

    // XCD-partitioned scatter params: chunk CE edges, 8 dst-range groups
    const int CE = 12544;                     // 49 * 256
    int M  = (E + CE - 1) / CE;               // 128 chunks
    int range = (N + 7) / 8;                  // 12500 nodes per group
    int sb = (N + 1023) / 1024;

    count_deg_x<<<8 * M, 256, 0, stream>>>(dst, cnt, E, CE, range, N);
    scan_partials<<<sb, 256, 0, stream>>>(cnt, bsum, N);
    scan_tops<<<1, 128, 0, stream>>>(bsum, &offs[N], sb, E);
    scan_write<<<sb, 256, 0, stream>>>(cnt, bsum, offs, N);
    fill_csr_x<<<8 * M, 256, 0, stream>>>(src, dst, cnt, offs, csr, E, CE, range, N);

    to_bf16<<<(N * HID / 4 + 255) / 256, 256, 0, stream>>>(x, bfB, N * HID / 4);

    int db = (N + 31) / 32;

    gather_mean<<<2048, 256, 0, stream>>>(bfB, offs, csr, aggb, N);
    dense_cat<<<db, 256, 0, stream>>>(aggb, x, Wl1, bl1, Wr1, H, bfA, N);

    gather_mean<<<2048, 256, 0, stream>>>(bfA, offs, csr, aggb, N);
    dense_cat<<<db, 256, 0, stream>>>(aggb, H, Wl2, bl2, Wr2, H, bfB, N);

    gather_mean<<<2048, 256, 0, stream>>>(bfB, offs, csr, aggb, N);
    dense_cat<<<db, 256, 0, stream>>>(aggb, H, Wl3, bl3, Wr3, out, (unsigned short*)nullptr, N);
}